// Round 6
// baseline (608.694 us; speedup 1.0000x reference)
//
#include <hip/hip_runtime.h>
#include <cmath>

#define N_NODES 100000
#define N_EDGES 1600000
#define F_IN 512
#define F_HID 128
#define F_OUT 64

#define SCAN_NB ((N_NODES + 255) / 256)   // 391 blocks

// ---- bucketed CSR-build params ----
#define BK_SHIFT 10                        // 1024 nodes per bucket
#define NBUK ((N_NODES + 1023) >> 10)      // 98 buckets
#define SCAP 24576                         // staging capacity/bucket (mean 16327, +65 sigma)
#define LSLOT 64                           // LDS slots per bucket
#define NBLK_A 512                         // partition blocks (R9: was 128 = half the CUs idle)
#define FILL_SPLIT 4                       // fill blocks per bucket (R9: was 1, 98 blocks total)
#define OV_CAP 4096                        // global overflow records

typedef __attribute__((ext_vector_type(8))) short short8;
typedef __attribute__((ext_vector_type(4))) float float4v;

// async global->LDS, 16B per lane; LDS dest is wave-uniform base + lane*16
#define GLOAD_LDS16(g, l)                                                      \
    __builtin_amdgcn_global_load_lds(                                          \
        (const __attribute__((address_space(1))) void*)(g),                    \
        (__attribute__((address_space(3))) void*)(l), 16, 0, 0)

__device__ __forceinline__ unsigned short f2bf(float f) {
    unsigned u = __builtin_bit_cast(unsigned, f);
    u += 0x7FFFu + ((u >> 16) & 1u);   // RNE
    return (unsigned short)(u >> 16);
}
__device__ __forceinline__ float bf2f(unsigned short s) {
    unsigned u = ((unsigned)s) << 16;
    return __builtin_bit_cast(float, u);
}
__device__ __forceinline__ float lo_bf(unsigned u) {
    return __builtin_bit_cast(float, u << 16);
}
__device__ __forceinline__ float hi_bf(unsigned u) {
    return __builtin_bit_cast(float, u & 0xFFFF0000u);
}
__device__ __forceinline__ short8 cvt8(float4 lo, float4 hi) {
    return short8{(short)f2bf(lo.x), (short)f2bf(lo.y), (short)f2bf(lo.z), (short)f2bf(lo.w),
                  (short)f2bf(hi.x), (short)f2bf(hi.y), (short)f2bf(hi.z), (short)f2bf(hi.w)};
}
__device__ __forceinline__ unsigned pack_bf2(float a, float b) {
    return (unsigned)f2bf(a) | ((unsigned)f2bf(b) << 16);
}

// counted vmcnt wait (template-dispatched literal; asm needs an immediate)
template <int N>
__device__ __forceinline__ void waitvm() {
    if constexpr (N == 0) asm volatile("s_waitcnt vmcnt(0)" ::: "memory");
    else if constexpr (N == 3) asm volatile("s_waitcnt vmcnt(3)" ::: "memory");
    else if constexpr (N == 6) asm volatile("s_waitcnt vmcnt(6)" ::: "memory");
    else static_assert(N == 0 || N == 3 || N == 6, "add literal");
}
#define LGKM0() asm volatile("s_waitcnt lgkmcnt(0)" ::: "memory")
#define BAR() __builtin_amdgcn_s_barrier()
#define SCHED0() __builtin_amdgcn_sched_barrier(0)

// ---------------- partition: edges -> per-bucket staging (+deg count fused) ----------------
// R9: 512 blocks (2/CU) instead of 128 (0.5/CU). PER rounded up to a multiple
// of 4 so the int4 edge loads stay 16B-aligned. All appends are atomic ->
// order-free, so more blocks changes only interleaving, not results.
__global__ __launch_bounds__(256) void partition_kernel(
    const int* __restrict__ src, const int* __restrict__ dst,
    int* __restrict__ deg, unsigned* __restrict__ staging, int* __restrict__ gcur,
    unsigned long long* __restrict__ ovbuf, int* __restrict__ ovcnt) {
    __shared__ unsigned buf[NBUK][LSLOT];
    __shared__ int cnt[NBUK];
    int tid = threadIdx.x;
    for (int b = tid; b < NBUK; b += 256) cnt[b] = 0;
    __syncthreads();
    constexpr int PER = (((N_EDGES + NBLK_A - 1) / NBLK_A) + 3) & ~3;   // 3128
    int e0 = blockIdx.x * PER;
    int e1 = min(e0 + PER, N_EDGES);

    auto body = [&](int d, int s) {
        atomicAdd(&deg[d], 1);
        int b = d >> BK_SHIFT;
        unsigned rec = (unsigned)s | ((unsigned)(d & 1023) << 17);
        int slot = atomicAdd(&cnt[b], 1);
        if (slot < LSLOT) {
            buf[b][slot] = rec;
        } else {  // rare LDS overflow: spill (src,dst) to global list
            int op = atomicAdd(ovcnt, 1);
            if (op < OV_CAP)
                ovbuf[op] = ((unsigned long long)(unsigned)d << 32) | (unsigned)s;
        }
    };
    auto drain = [&](void) {
        for (int b = tid; b < NBUK; b += 256) {
            int c = min(cnt[b], LSLOT);
            int full = c & ~15;
            if (full > 0) {
                int pos = atomicAdd(&gcur[b], full);
                if (pos + full <= SCAP) {
                    unsigned* dp = &staging[(size_t)b * SCAP + pos];
                    for (int i = 0; i < full; ++i) dp[i] = buf[b][i];
                }
                for (int i = 0; i < c - full; ++i) buf[b][i] = buf[b][full + i];
            }
            cnt[b] = c - full;
        }
    };

    int base = e0;
    for (; base + 1024 <= e1; base += 1024) {
        int e = base + tid * 4;
        int4 dv = *(const int4*)(dst + e);   // 16B vectorized edge loads
        int4 sv = *(const int4*)(src + e);
        body(dv.x, sv.x);
        body(dv.y, sv.y);
        body(dv.z, sv.z);
        body(dv.w, sv.w);
        __syncthreads();
        drain();
        __syncthreads();
    }
    // tail (<1024 edges), scalar
    for (int e = base + tid; e < e1; e += 256) body(dst[e], src[e]);
    __syncthreads();
    drain();
    __syncthreads();
    // final flush of remainders
    for (int b = tid; b < NBUK; b += 256) {
        int c = cnt[b];
        if (c > 0) {
            int pos = atomicAdd(&gcur[b], c);
            if (pos + c <= SCAP)
                for (int i = 0; i < c; ++i) staging[(size_t)b * SCAP + pos + i] = buf[b][i];
        }
    }
}

// ---------------- fill: FILL_SPLIT blocks per bucket -> CSR scatter ----------------
// R9: 98 -> 392 blocks. Slices stride the staging in interleaved 1KB chunks
// (each 256-thread group reads contiguous); cursor atomics make slice order
// irrelevant. Overflow replay runs on slice 0 only (no duplicates).
__global__ __launch_bounds__(256) void fill_kernel(
    const unsigned* __restrict__ staging, const int* __restrict__ gcur,
    int* __restrict__ cursor, int* __restrict__ csr_src,
    const unsigned long long* __restrict__ ovbuf, const int* __restrict__ ovcnt) {
    int b = blockIdx.x / FILL_SPLIT;
    int slice = blockIdx.x - b * FILL_SPLIT;
    int node0 = b << BK_SHIFT;
    int n = gcur[b];
    if (n > SCAP) n = SCAP;
    const unsigned* sp = &staging[(size_t)b * SCAP];
    for (int i = slice * 256 + threadIdx.x; i < n; i += 256 * FILL_SPLIT) {
        unsigned rec = sp[i];
        int s = (int)(rec & 0x1FFFFu);
        int d = node0 + (int)(rec >> 17);
        int pos = atomicAdd(&cursor[d], 1);
        csr_src[pos] = s;
    }
    if (slice == 0) {
        int oc = *ovcnt;
        if (oc > OV_CAP) oc = OV_CAP;
        for (int i = threadIdx.x; i < oc; i += 256) {
            unsigned long long r = ovbuf[i];
            int d = (int)(r >> 32);
            if ((d >> BK_SHIFT) == b) {
                int pos = atomicAdd(&cursor[d], 1);
                csr_src[pos] = (int)(r & 0xffffffffu);
            }
        }
    }
}

// ---------------- scans ----------------

__global__ __launch_bounds__(256) void block_sum_kernel(const int* __restrict__ deg,
                                                        int* __restrict__ bsum, int n) {
    int g = blockIdx.x * 256 + threadIdx.x;
    int v = (g < n) ? deg[g] : 0;
    __shared__ int ws[4];
    int lane = threadIdx.x & 63;
    int w = threadIdx.x >> 6;
#pragma unroll
    for (int o = 32; o > 0; o >>= 1) v += __shfl_down(v, o, 64);
    if (lane == 0) ws[w] = v;
    __syncthreads();
    if (threadIdx.x == 0) bsum[blockIdx.x] = ws[0] + ws[1] + ws[2] + ws[3];
}

__global__ __launch_bounds__(512) void scan_partials_kernel(int* __restrict__ bsum, int nb) {
    __shared__ int t[512];
    int tid = threadIdx.x;
    int v = (tid < nb) ? bsum[tid] : 0;
    t[tid] = v;
    __syncthreads();
    for (int d = 1; d < 512; d <<= 1) {
        int u = (tid >= d) ? t[tid - d] : 0;
        __syncthreads();
        t[tid] += u;
        __syncthreads();
    }
    if (tid < nb) bsum[tid] = t[tid] - v;  // exclusive
}

__global__ __launch_bounds__(256) void scan_final_kernel(const int* __restrict__ deg,
                                                         const int* __restrict__ bsum,
                                                         int* __restrict__ row_ptr,
                                                         int* __restrict__ cursor,
                                                         float* __restrict__ dinv, int n) {
    __shared__ int t[256];
    int g = blockIdx.x * 256 + threadIdx.x;
    int tid = threadIdx.x;
    int v = (g < n) ? deg[g] : 0;
    t[tid] = v;
    __syncthreads();
    for (int d = 1; d < 256; d <<= 1) {
        int u = (tid >= d) ? t[tid - d] : 0;
        __syncthreads();
        t[tid] += u;
        __syncthreads();
    }
    int off = bsum[blockIdx.x] + t[tid] - v;
    if (g < n) {
        row_ptr[g] = off;
        cursor[g] = off;
        dinv[g] = rsqrtf((float)(v + 1));
    }
    if (g == n - 1) row_ptr[n] = off + v;
}

// ---------------- W transpose+convert: Wt[n][k] bf16 ----------------

__global__ void transpose_w_kernel(const float* __restrict__ W1, const float* __restrict__ W2,
                                   unsigned short* __restrict__ Wt1,
                                   unsigned short* __restrict__ Wt2) {
    int g = blockIdx.x * 256 + threadIdx.x;
    if (g < F_HID * F_IN) {               // Wt1: [128][512]
        int n = g >> 9, k = g & 511;
        Wt1[g] = f2bf(W1[k * F_HID + n]);
    } else {
        int h = g - F_HID * F_IN;         // Wt2: [64][128]
        if (h < F_OUT * F_HID) {
            int n = h >> 7, k = h & 127;
            Wt2[h] = f2bf(W2[k * F_OUT + n]);
        }
    }
}

// ---------------- LDS-staged MFMA GEMM, counted-vmcnt pipeline (T3+T4) ----------------

template <int BN, int K, bool A_BF16>
__global__ __launch_bounds__(256, 3) void gemm_lds_kernel(
    const void* __restrict__ Araw, const unsigned short* __restrict__ Wt,
    const float* __restrict__ dinv, unsigned short* __restrict__ out, int N) {
    constexpr int NCT = BN / 16;
    constexpr int AE = A_BF16 ? 2 : 4;         // A element bytes
    constexpr int SLOTS_A = (32 * AE) / 16;    // 16B slots per row per 32-k chunk (4 or 8)
    constexpr int MA = SLOTS_A - 1;
    constexpr int ABYTES = 128 * 32 * AE;      // per A buffer (8K or 16K)
    constexpr int BBYTES = BN * 32 * 2;        // per B buffer (4K or 8K)
    constexpr int NT = K / 32;
    constexpr int SL = (128 * SLOTS_A + BN * 4) / 256;  // gload_lds per stage: 6 (gemm1) / 3 (gemm2)

    __shared__ __align__(128) char Abuf[2][ABYTES];
    __shared__ __align__(128) char Bbuf[2][BBYTES];

    const char* Ab = (const char*)Araw;
    const char* Bb = (const char*)Wt;
    int tid = threadIdx.x;
    int lane = tid & 63;
    int wv = tid >> 6;
    int row0 = blockIdx.x * 128;
    int l15 = lane & 15;
    int q = lane >> 4;

    float4v acc[2][NCT] = {};

    auto stage = [&](int buf, int k0) {
        // A: 128 rows x 32 elems, 16B chunks; chunk c -> row c/SLOTS_A, slot c%SLOTS_A
        constexpr int CA = 128 * SLOTS_A;
#pragma unroll
        for (int i = 0; i < CA / 256; ++i) {
            int c = i * 256 + tid;
            int cw = i * 256 + (tid & ~63);      // wave-uniform chunk base
            int row = c / SLOTS_A;
            int s = c & MA;
            int g = s ^ (row & MA);              // inverse swizzle on SOURCE
            int rg = row0 + row;
            if (rg >= N) rg = N - 1;             // clamp (last block tail)
            GLOAD_LDS16(Ab + ((size_t)rg * K + k0) * AE + g * 16,
                        &Abuf[buf][cw * 16]);
        }
        // B: BN cols x 32 k bf16 (64B per col = 4 slots)
        constexpr int CB = BN * 4;
#pragma unroll
        for (int i = 0; i < CB / 256; ++i) {
            int c = i * 256 + tid;
            int cw = i * 256 + (tid & ~63);
            int col = c >> 2;
            int s = c & 3;
            int g = s ^ (col & 3);
            GLOAD_LDS16(Bb + ((size_t)col * K + k0) * 2 + g * 16,
                        &Bbuf[buf][cw * 16]);
        }
    };

    auto compute = [&](int buf) {
        const char* Ac = Abuf[buf];
        const char* Bc = Bbuf[buf];
        int lr0 = wv * 32 + l15;
        int lr1 = lr0 + 16;
        short8 a0, a1;
        if constexpr (A_BF16) {
            int s0 = q ^ (lr0 & 3);
            int s1 = q ^ (lr1 & 3);
            a0 = *(const short8*)(Ac + lr0 * 64 + s0 * 16);
            a1 = *(const short8*)(Ac + lr1 * 64 + s1 * 16);
        } else {
            int r7a = lr0 & 7, r7b = lr1 & 7;
            float4 f0 = *(const float4*)(Ac + lr0 * 128 + ((2 * q) ^ r7a) * 16);
            float4 f1 = *(const float4*)(Ac + lr0 * 128 + ((2 * q + 1) ^ r7a) * 16);
            float4 f2 = *(const float4*)(Ac + lr1 * 128 + ((2 * q) ^ r7b) * 16);
            float4 f3 = *(const float4*)(Ac + lr1 * 128 + ((2 * q + 1) ^ r7b) * 16);
            a0 = cvt8(f0, f1);
            a1 = cvt8(f2, f3);
        }
#pragma unroll
        for (int ct = 0; ct < NCT; ++ct) {
            int col = ct * 16 + l15;
            int sb = q ^ (col & 3);
            short8 b = *(const short8*)(Bc + col * 64 + sb * 16);
            acc[0][ct] = __builtin_amdgcn_mfma_f32_16x16x32_bf16(a0, b, acc[0][ct], 0, 0, 0);
            acc[1][ct] = __builtin_amdgcn_mfma_f32_16x16x32_bf16(a1, b, acc[1][ct], 0, 0, 0);
        }
    };

    // prologue: 2 tiles in flight (2*SL loads outstanding)
    stage(0, 0);
    stage(1, 32);
#pragma unroll 1
    for (int t = 0; t < NT - 2; ++t) {
        waitvm<SL>();                 // stage(t) landed; stage(t+1) stays in flight
        BAR();
        SCHED0();
        compute(t & 1);
        LGKM0();                      // all ds_reads of buf t&1 executed
        BAR();
        SCHED0();
        stage(t & 1, (t + 2) * 32);   // overwrite consumed buffer with tile t+2
    }
    // tile NT-2 (stage NT-1 still in flight)
    waitvm<SL>();
    BAR();
    SCHED0();
    compute((NT - 2) & 1);
    // tile NT-1 (final drain)
    waitvm<0>();
    BAR();
    SCHED0();
    compute((NT - 1) & 1);

    // epilogue: dinv scale + bf16 store
#pragma unroll
    for (int rt = 0; rt < 2; ++rt) {
#pragma unroll
        for (int reg = 0; reg < 4; ++reg) {
            int row = row0 + wv * 32 + rt * 16 + q * 4 + reg;
            if (row < N) {
                float sc = dinv[row];
#pragma unroll
                for (int ct = 0; ct < NCT; ++ct) {
                    out[(size_t)row * BN + ct * 16 + l15] = f2bf(acc[rt][ct][reg] * sc);
                }
            }
        }
    }
}

// ---------------- aggregation v2: 2 nodes/warp, 8-deep gather pipeline ----------------

__global__ __launch_bounds__(256) void agg1_kernel(
    const uint2* __restrict__ g1v, const int* __restrict__ row_ptr,
    const int* __restrict__ csr_src, const float* __restrict__ dinv,
    const float4* __restrict__ b1v, uint2* __restrict__ h1v) {
    int tid = threadIdx.x;
    int wv = tid >> 6;
    int lane = tid & 63;
    int half = lane >> 5;
    int hl = lane & 31;
    int node = blockIdx.x * 8 + wv * 2 + half;
    uint2 u = g1v[(size_t)node * 32 + hl];
    float a0 = lo_bf(u.x), a1 = hi_bf(u.x), a2 = lo_bf(u.y), a3 = hi_bf(u.y);
    int e = row_ptr[node], end = row_ptr[node + 1];
    for (; e + 8 <= end; e += 8) {
        int j0 = csr_src[e + 0], j1 = csr_src[e + 1], j2 = csr_src[e + 2], j3 = csr_src[e + 3];
        int j4 = csr_src[e + 4], j5 = csr_src[e + 5], j6 = csr_src[e + 6], j7 = csr_src[e + 7];
        uint2 v0 = g1v[(size_t)j0 * 32 + hl];
        uint2 v1 = g1v[(size_t)j1 * 32 + hl];
        uint2 v2 = g1v[(size_t)j2 * 32 + hl];
        uint2 v3 = g1v[(size_t)j3 * 32 + hl];
        uint2 v4 = g1v[(size_t)j4 * 32 + hl];
        uint2 v5 = g1v[(size_t)j5 * 32 + hl];
        uint2 v6 = g1v[(size_t)j6 * 32 + hl];
        uint2 v7 = g1v[(size_t)j7 * 32 + hl];
        a0 += ((lo_bf(v0.x) + lo_bf(v1.x)) + (lo_bf(v2.x) + lo_bf(v3.x))) +
              ((lo_bf(v4.x) + lo_bf(v5.x)) + (lo_bf(v6.x) + lo_bf(v7.x)));
        a1 += ((hi_bf(v0.x) + hi_bf(v1.x)) + (hi_bf(v2.x) + hi_bf(v3.x))) +
              ((hi_bf(v4.x) + hi_bf(v5.x)) + (hi_bf(v6.x) + hi_bf(v7.x)));
        a2 += ((lo_bf(v0.y) + lo_bf(v1.y)) + (lo_bf(v2.y) + lo_bf(v3.y))) +
              ((lo_bf(v4.y) + lo_bf(v5.y)) + (lo_bf(v6.y) + lo_bf(v7.y)));
        a3 += ((hi_bf(v0.y) + hi_bf(v1.y)) + (hi_bf(v2.y) + hi_bf(v3.y))) +
              ((hi_bf(v4.y) + hi_bf(v5.y)) + (hi_bf(v6.y) + hi_bf(v7.y)));
    }
    for (; e + 2 <= end; e += 2) {
        int j0 = csr_src[e + 0], j1 = csr_src[e + 1];
        uint2 v0 = g1v[(size_t)j0 * 32 + hl];
        uint2 v1 = g1v[(size_t)j1 * 32 + hl];
        a0 += lo_bf(v0.x) + lo_bf(v1.x);
        a1 += hi_bf(v0.x) + hi_bf(v1.x);
        a2 += lo_bf(v0.y) + lo_bf(v1.y);
        a3 += hi_bf(v0.y) + hi_bf(v1.y);
    }
    for (; e < end; ++e) {
        uint2 v0 = g1v[(size_t)csr_src[e] * 32 + hl];
        a0 += lo_bf(v0.x);
        a1 += hi_bf(v0.x);
        a2 += lo_bf(v0.y);
        a3 += hi_bf(v0.y);
    }
    float d = dinv[node];
    float4 b = b1v[hl];
    float r0 = fmaxf(d * a0 + b.x, 0.0f);
    float r1 = fmaxf(d * a1 + b.y, 0.0f);
    float r2 = fmaxf(d * a2 + b.z, 0.0f);
    float r3 = fmaxf(d * a3 + b.w, 0.0f);
    h1v[(size_t)node * 32 + hl] = uint2{pack_bf2(r0, r1), pack_bf2(r2, r3)};
}

__global__ __launch_bounds__(256) void agg2_lsm_kernel(
    const unsigned* __restrict__ g2v, const int* __restrict__ row_ptr,
    const int* __restrict__ csr_src, const float* __restrict__ dinv,
    const float2* __restrict__ b2v, float2* __restrict__ outv) {
    int tid = threadIdx.x;
    int wv = tid >> 6;
    int lane = tid & 63;
    int half = lane >> 5;
    int hl = lane & 31;
    int node = blockIdx.x * 8 + wv * 2 + half;
    unsigned u = g2v[(size_t)node * 32 + hl];
    float a0 = lo_bf(u), a1 = hi_bf(u);
    int e = row_ptr[node], end = row_ptr[node + 1];
    for (; e + 8 <= end; e += 8) {
        int j0 = csr_src[e + 0], j1 = csr_src[e + 1], j2 = csr_src[e + 2], j3 = csr_src[e + 3];
        int j4 = csr_src[e + 4], j5 = csr_src[e + 5], j6 = csr_src[e + 6], j7 = csr_src[e + 7];
        unsigned v0 = g2v[(size_t)j0 * 32 + hl];
        unsigned v1 = g2v[(size_t)j1 * 32 + hl];
        unsigned v2 = g2v[(size_t)j2 * 32 + hl];
        unsigned v3 = g2v[(size_t)j3 * 32 + hl];
        unsigned v4 = g2v[(size_t)j4 * 32 + hl];
        unsigned v5 = g2v[(size_t)j5 * 32 + hl];
        unsigned v6 = g2v[(size_t)j6 * 32 + hl];
        unsigned v7 = g2v[(size_t)j7 * 32 + hl];
        a0 += ((lo_bf(v0) + lo_bf(v1)) + (lo_bf(v2) + lo_bf(v3))) +
              ((lo_bf(v4) + lo_bf(v5)) + (lo_bf(v6) + lo_bf(v7)));
        a1 += ((hi_bf(v0) + hi_bf(v1)) + (hi_bf(v2) + hi_bf(v3))) +
              ((hi_bf(v4) + hi_bf(v5)) + (hi_bf(v6) + hi_bf(v7)));
    }
    for (; e + 2 <= end; e += 2) {
        unsigned v0 = g2v[(size_t)csr_src[e + 0] * 32 + hl];
        unsigned v1 = g2v[(size_t)csr_src[e + 1] * 32 + hl];
        a0 += lo_bf(v0) + lo_bf(v1);
        a1 += hi_bf(v0) + hi_bf(v1);
    }
    for (; e < end; ++e) {
        unsigned v0 = g2v[(size_t)csr_src[e] * 32 + hl];
        a0 += lo_bf(v0);
        a1 += hi_bf(v0);
    }
    float d = dinv[node];
    float2 b = b2v[hl];
    float v0 = d * a0 + b.x;
    float v1 = d * a1 + b.y;
    // log-softmax over 64 classes: per-lane pair + 32-lane half reduction
    // (xor offsets <=16 stay within the 32-lane half)
    float m = fmaxf(v0, v1);
#pragma unroll
    for (int o = 16; o > 0; o >>= 1) m = fmaxf(m, __shfl_xor(m, o, 64));
    float s = __expf(v0 - m) + __expf(v1 - m);
#pragma unroll
    for (int o = 16; o > 0; o >>= 1) s += __shfl_xor(s, o, 64);
    float ls = __logf(s);
    outv[(size_t)node * 32 + hl] = float2{v0 - m - ls, v1 - m - ls};
}

// ---------------- launch ----------------

extern "C" void kernel_launch(void* const* d_in, const int* in_sizes, int n_in,
                              void* d_out, int out_size, void* d_ws, size_t ws_size,
                              hipStream_t stream) {
    const float* x  = (const float*)d_in[0];
    const int* eidx = (const int*)d_in[1];
    const float* W1 = (const float*)d_in[2];
    const float* b1 = (const float*)d_in[3];
    const float* W2 = (const float*)d_in[4];
    const float* b2 = (const float*)d_in[5];
    float* out = (float*)d_out;
    const int* src = eidx;
    const int* dst = eidx + N_EDGES;

    char* base = (char*)d_ws;
    size_t off = 0;
    auto alloc = [&](size_t bytes) -> void* {
        void* p = base + off;
        off += (bytes + 255) & ~(size_t)255;
        return p;
    };
    // zero-init region: [deg | gcur | ovcnt] — one memset
    int* zbase    = (int*)alloc((size_t)(N_NODES + NBUK + 64) * 4);
    int* deg      = zbase;
    int* gcur     = zbase + N_NODES;
    int* ovcnt    = zbase + N_NODES + NBUK;
    int* row_ptr  = (int*)alloc((size_t)(N_NODES + 1) * 4);
    int* cursor   = (int*)alloc((size_t)N_NODES * 4);
    float* dinv   = (float*)alloc((size_t)N_NODES * 4);
    int* bsum     = (int*)alloc((size_t)SCAN_NB * 4);
    unsigned* staging = (unsigned*)alloc((size_t)NBUK * SCAP * 4);   // 9.6 MB
    unsigned long long* ovbuf = (unsigned long long*)alloc((size_t)OV_CAP * 8);
    int* csr_src  = (int*)alloc((size_t)N_EDGES * 4);
    unsigned short* Wt1 = (unsigned short*)alloc((size_t)F_HID * F_IN * 2);
    unsigned short* Wt2 = (unsigned short*)alloc((size_t)F_OUT * F_HID * 2);
    unsigned short* g1  = (unsigned short*)alloc((size_t)N_NODES * F_HID * 2);
    unsigned short* h1  = (unsigned short*)alloc((size_t)N_NODES * F_HID * 2);
    unsigned short* g2  = g1;  // g1 dead after agg1

    hipMemsetAsync(zbase, 0, (size_t)(N_NODES + NBUK + 64) * 4, stream);
    partition_kernel<<<NBLK_A, 256, 0, stream>>>(src, dst, deg, staging, gcur, ovbuf, ovcnt);
    block_sum_kernel<<<SCAN_NB, 256, 0, stream>>>(deg, bsum, N_NODES);
    scan_partials_kernel<<<1, 512, 0, stream>>>(bsum, SCAN_NB);
    scan_final_kernel<<<SCAN_NB, 256, 0, stream>>>(deg, bsum, row_ptr, cursor, dinv, N_NODES);
    fill_kernel<<<NBUK * FILL_SPLIT, 256, 0, stream>>>(staging, gcur, cursor, csr_src, ovbuf, ovcnt);
    transpose_w_kernel<<<(F_HID * F_IN + F_OUT * F_HID + 255) / 256, 256, 0, stream>>>(
        W1, W2, Wt1, Wt2);

    int gblocks = (N_NODES + 127) / 128;  // 782
    gemm_lds_kernel<F_HID, F_IN, false><<<gblocks, 256, 0, stream>>>(
        (const void*)x, Wt1, dinv, g1, N_NODES);
    agg1_kernel<<<N_NODES / 8, 256, 0, stream>>>(
        (const uint2*)g1, row_ptr, csr_src, dinv, (const float4*)b1, (uint2*)h1);

    gemm_lds_kernel<F_OUT, F_HID, true><<<gblocks, 256, 0, stream>>>(
        (const void*)h1, Wt2, dinv, g2, N_NODES);
    agg2_lsm_kernel<<<N_NODES / 8, 256, 0, stream>>>(
        (const unsigned*)g2, row_ptr, csr_src, dinv, (const float2*)b2, (float2*)out);
}

// Round 7
// 557.493 us; speedup vs baseline: 1.0918x; 1.0918x over previous
//
#include <hip/hip_runtime.h>
#include <cmath>

#define N_NODES 100000
#define N_EDGES 1600000
#define F_IN 512
#define F_HID 128
#define F_OUT 64

#define SCAN_NB ((N_NODES + 255) / 256)   // 391 blocks

// ---- bucketed CSR-build params ----
#define BK_SHIFT 10                        // 1024 nodes per bucket
#define NBUK ((N_NODES + 1023) >> 10)      // 98 buckets
#define SCAP 24576                         // staging capacity/bucket (mean 16327, +65 sigma)
#define LSLOT 64                           // LDS slots per bucket
#define NBLK_A 512                         // partition blocks (2/CU)
#define FILL_SPLIT 8                       // R10: slice-blocks per bucket, disjoint node ranges
#define NPS (1024 / FILL_SPLIT)            // 128 nodes per slice
#define OV_CAP 4096                        // global overflow records

typedef __attribute__((ext_vector_type(8))) short short8;
typedef __attribute__((ext_vector_type(4))) float float4v;

// async global->LDS, 16B per lane; LDS dest is wave-uniform base + lane*16
#define GLOAD_LDS16(g, l)                                                      \
    __builtin_amdgcn_global_load_lds(                                          \
        (const __attribute__((address_space(1))) void*)(g),                    \
        (__attribute__((address_space(3))) void*)(l), 16, 0, 0)

__device__ __forceinline__ unsigned short f2bf(float f) {
    unsigned u = __builtin_bit_cast(unsigned, f);
    u += 0x7FFFu + ((u >> 16) & 1u);   // RNE
    return (unsigned short)(u >> 16);
}
__device__ __forceinline__ float bf2f(unsigned short s) {
    unsigned u = ((unsigned)s) << 16;
    return __builtin_bit_cast(float, u);
}
__device__ __forceinline__ float lo_bf(unsigned u) {
    return __builtin_bit_cast(float, u << 16);
}
__device__ __forceinline__ float hi_bf(unsigned u) {
    return __builtin_bit_cast(float, u & 0xFFFF0000u);
}
__device__ __forceinline__ short8 cvt8(float4 lo, float4 hi) {
    return short8{(short)f2bf(lo.x), (short)f2bf(lo.y), (short)f2bf(lo.z), (short)f2bf(lo.w),
                  (short)f2bf(hi.x), (short)f2bf(hi.y), (short)f2bf(hi.z), (short)f2bf(hi.w)};
}
__device__ __forceinline__ unsigned pack_bf2(float a, float b) {
    return (unsigned)f2bf(a) | ((unsigned)f2bf(b) << 16);
}

// counted vmcnt wait (template-dispatched literal; asm needs an immediate)
template <int N>
__device__ __forceinline__ void waitvm() {
    if constexpr (N == 0) asm volatile("s_waitcnt vmcnt(0)" ::: "memory");
    else if constexpr (N == 3) asm volatile("s_waitcnt vmcnt(3)" ::: "memory");
    else if constexpr (N == 6) asm volatile("s_waitcnt vmcnt(6)" ::: "memory");
    else static_assert(N == 0 || N == 3 || N == 6, "add literal");
}
#define LGKM0() asm volatile("s_waitcnt lgkmcnt(0)" ::: "memory")
#define BAR() __builtin_amdgcn_s_barrier()
#define SCHED0() __builtin_amdgcn_sched_barrier(0)

// ---------------- partition: edges -> per-bucket staging (+deg count fused) ----------------
__global__ __launch_bounds__(256) void partition_kernel(
    const int* __restrict__ src, const int* __restrict__ dst,
    int* __restrict__ deg, unsigned* __restrict__ staging, int* __restrict__ gcur,
    unsigned long long* __restrict__ ovbuf, int* __restrict__ ovcnt) {
    __shared__ unsigned buf[NBUK][LSLOT];
    __shared__ int cnt[NBUK];
    int tid = threadIdx.x;
    for (int b = tid; b < NBUK; b += 256) cnt[b] = 0;
    __syncthreads();
    constexpr int PER = (((N_EDGES + NBLK_A - 1) / NBLK_A) + 3) & ~3;   // 3128
    int e0 = blockIdx.x * PER;
    int e1 = min(e0 + PER, N_EDGES);

    auto body = [&](int d, int s) {
        atomicAdd(&deg[d], 1);
        int b = d >> BK_SHIFT;
        unsigned rec = (unsigned)s | ((unsigned)(d & 1023) << 17);
        int slot = atomicAdd(&cnt[b], 1);
        if (slot < LSLOT) {
            buf[b][slot] = rec;
        } else {  // rare LDS overflow: spill (src,dst) to global list
            int op = atomicAdd(ovcnt, 1);
            if (op < OV_CAP)
                ovbuf[op] = ((unsigned long long)(unsigned)d << 32) | (unsigned)s;
        }
    };
    auto drain = [&](void) {
        for (int b = tid; b < NBUK; b += 256) {
            int c = min(cnt[b], LSLOT);
            int full = c & ~15;
            if (full > 0) {
                int pos = atomicAdd(&gcur[b], full);
                if (pos + full <= SCAP) {
                    unsigned* dp = &staging[(size_t)b * SCAP + pos];
                    for (int i = 0; i < full; ++i) dp[i] = buf[b][i];
                }
                for (int i = 0; i < c - full; ++i) buf[b][i] = buf[b][full + i];
            }
            cnt[b] = c - full;
        }
    };

    int base = e0;
    for (; base + 1024 <= e1; base += 1024) {
        int e = base + tid * 4;
        int4 dv = *(const int4*)(dst + e);   // 16B vectorized edge loads
        int4 sv = *(const int4*)(src + e);
        body(dv.x, sv.x);
        body(dv.y, sv.y);
        body(dv.z, sv.z);
        body(dv.w, sv.w);
        __syncthreads();
        drain();
        __syncthreads();
    }
    // tail (<1024 edges), scalar
    for (int e = base + tid; e < e1; e += 256) body(dst[e], src[e]);
    __syncthreads();
    drain();
    __syncthreads();
    // final flush of remainders
    for (int b = tid; b < NBUK; b += 256) {
        int c = cnt[b];
        if (c > 0) {
            int pos = atomicAdd(&gcur[b], c);
            if (pos + c <= SCAP)
                for (int i = 0; i < c; ++i) staging[(size_t)b * SCAP + pos + i] = buf[b][i];
        }
    }
}

// ---------------- fill v3: slice-owned node ranges + LDS cursors ----------------
// R10: R9's 4 slice-blocks hammered the SAME cursor lines from different XCDs
// (fill 125-136us, VALUBusy 0.3%, hbm 0.7 TB/s = device-scope atomic ping-pong).
// Now each slice-block OWNS nodes [node0 + slice*128, +128): LDS cursors are
// initialized straight from row_ptr (no counting pass, no global cursor array),
// position resolution is an LDS atomic (~30cyc, zero cross-XCD traffic).
// Cost: each slice scans the whole bucket staging (8x read amp, L2-resident).
__global__ __launch_bounds__(256) void fill_kernel(
    const unsigned* __restrict__ staging, const int* __restrict__ gcur,
    const int* __restrict__ row_ptr, int* __restrict__ csr_src,
    const unsigned long long* __restrict__ ovbuf, const int* __restrict__ ovcnt) {
    int b = blockIdx.x / FILL_SPLIT;
    int slice = blockIdx.x - b * FILL_SPLIT;
    int dl0 = slice * NPS;                  // first local node of this slice
    int node0 = (b << BK_SHIFT) + dl0;
    __shared__ int lcur[NPS];
    int tid = threadIdx.x;
    if (tid < NPS) {
        int nd = node0 + tid;
        lcur[tid] = (nd < N_NODES) ? row_ptr[nd] : 0;
    }
    __syncthreads();

    int n = gcur[b];
    if (n > SCAP) n = SCAP;
    const unsigned* sp = &staging[(size_t)b * SCAP];

    auto process = [&](unsigned rec) {
        int dl = (int)(rec >> 17) - dl0;
        if ((unsigned)dl < (unsigned)NPS) {
            int pos = atomicAdd(&lcur[dl], 1);
            csr_src[pos] = (int)(rec & 0x1FFFFu);
        }
    };

    // vectorized scan: thread t covers [4t, 4t+4) stepping 1024 -> all multiples of 4 < n
    int i = tid * 4;
    for (; i + 4 <= n; i += 1024) {
        uint4 r = *(const uint4*)(sp + i);
        process(r.x);
        process(r.y);
        process(r.z);
        process(r.w);
    }
    int tail0 = n & ~3;
    if (tid < (n - tail0)) process(sp[tail0 + tid]);

    // overflow replay (rare), same ownership filter
    int oc = *ovcnt;
    if (oc > OV_CAP) oc = OV_CAP;
    for (int k = tid; k < oc; k += 256) {
        unsigned long long r = ovbuf[k];
        int d = (int)(r >> 32);
        int dl = d - node0;
        if ((d >> BK_SHIFT) == b && (unsigned)dl < (unsigned)NPS) {
            int pos = atomicAdd(&lcur[dl], 1);
            csr_src[pos] = (int)(r & 0xffffffffu);
        }
    }
}

// ---------------- scans ----------------

__global__ __launch_bounds__(256) void block_sum_kernel(const int* __restrict__ deg,
                                                        int* __restrict__ bsum, int n) {
    int g = blockIdx.x * 256 + threadIdx.x;
    int v = (g < n) ? deg[g] : 0;
    __shared__ int ws[4];
    int lane = threadIdx.x & 63;
    int w = threadIdx.x >> 6;
#pragma unroll
    for (int o = 32; o > 0; o >>= 1) v += __shfl_down(v, o, 64);
    if (lane == 0) ws[w] = v;
    __syncthreads();
    if (threadIdx.x == 0) bsum[blockIdx.x] = ws[0] + ws[1] + ws[2] + ws[3];
}

__global__ __launch_bounds__(512) void scan_partials_kernel(int* __restrict__ bsum, int nb) {
    __shared__ int t[512];
    int tid = threadIdx.x;
    int v = (tid < nb) ? bsum[tid] : 0;
    t[tid] = v;
    __syncthreads();
    for (int d = 1; d < 512; d <<= 1) {
        int u = (tid >= d) ? t[tid - d] : 0;
        __syncthreads();
        t[tid] += u;
        __syncthreads();
    }
    if (tid < nb) bsum[tid] = t[tid] - v;  // exclusive
}

__global__ __launch_bounds__(256) void scan_final_kernel(const int* __restrict__ deg,
                                                         const int* __restrict__ bsum,
                                                         int* __restrict__ row_ptr,
                                                         float* __restrict__ dinv, int n) {
    __shared__ int t[256];
    int g = blockIdx.x * 256 + threadIdx.x;
    int tid = threadIdx.x;
    int v = (g < n) ? deg[g] : 0;
    t[tid] = v;
    __syncthreads();
    for (int d = 1; d < 256; d <<= 1) {
        int u = (tid >= d) ? t[tid - d] : 0;
        __syncthreads();
        t[tid] += u;
        __syncthreads();
    }
    int off = bsum[blockIdx.x] + t[tid] - v;
    if (g < n) {
        row_ptr[g] = off;
        dinv[g] = rsqrtf((float)(v + 1));
    }
    if (g == n - 1) row_ptr[n] = off + v;
}

// ---------------- W transpose+convert: Wt[n][k] bf16 ----------------

__global__ void transpose_w_kernel(const float* __restrict__ W1, const float* __restrict__ W2,
                                   unsigned short* __restrict__ Wt1,
                                   unsigned short* __restrict__ Wt2) {
    int g = blockIdx.x * 256 + threadIdx.x;
    if (g < F_HID * F_IN) {               // Wt1: [128][512]
        int n = g >> 9, k = g & 511;
        Wt1[g] = f2bf(W1[k * F_HID + n]);
    } else {
        int h = g - F_HID * F_IN;         // Wt2: [64][128]
        if (h < F_OUT * F_HID) {
            int n = h >> 7, k = h & 127;
            Wt2[h] = f2bf(W2[k * F_OUT + n]);
        }
    }
}

// ---------------- LDS-staged MFMA GEMM, counted-vmcnt pipeline (T3+T4) ----------------

template <int BN, int K, bool A_BF16>
__global__ __launch_bounds__(256, 3) void gemm_lds_kernel(
    const void* __restrict__ Araw, const unsigned short* __restrict__ Wt,
    const float* __restrict__ dinv, unsigned short* __restrict__ out, int N) {
    constexpr int NCT = BN / 16;
    constexpr int AE = A_BF16 ? 2 : 4;         // A element bytes
    constexpr int SLOTS_A = (32 * AE) / 16;    // 16B slots per row per 32-k chunk (4 or 8)
    constexpr int MA = SLOTS_A - 1;
    constexpr int ABYTES = 128 * 32 * AE;      // per A buffer (8K or 16K)
    constexpr int BBYTES = BN * 32 * 2;        // per B buffer (4K or 8K)
    constexpr int NT = K / 32;
    constexpr int SL = (128 * SLOTS_A + BN * 4) / 256;  // gload_lds per stage: 6 (gemm1) / 3 (gemm2)

    __shared__ __align__(128) char Abuf[2][ABYTES];
    __shared__ __align__(128) char Bbuf[2][BBYTES];

    const char* Ab = (const char*)Araw;
    const char* Bb = (const char*)Wt;
    int tid = threadIdx.x;
    int lane = tid & 63;
    int wv = tid >> 6;
    int row0 = blockIdx.x * 128;
    int l15 = lane & 15;
    int q = lane >> 4;

    float4v acc[2][NCT] = {};

    auto stage = [&](int buf, int k0) {
        // A: 128 rows x 32 elems, 16B chunks; chunk c -> row c/SLOTS_A, slot c%SLOTS_A
        constexpr int CA = 128 * SLOTS_A;
#pragma unroll
        for (int i = 0; i < CA / 256; ++i) {
            int c = i * 256 + tid;
            int cw = i * 256 + (tid & ~63);      // wave-uniform chunk base
            int row = c / SLOTS_A;
            int s = c & MA;
            int g = s ^ (row & MA);              // inverse swizzle on SOURCE
            int rg = row0 + row;
            if (rg >= N) rg = N - 1;             // clamp (last block tail)
            GLOAD_LDS16(Ab + ((size_t)rg * K + k0) * AE + g * 16,
                        &Abuf[buf][cw * 16]);
        }
        // B: BN cols x 32 k bf16 (64B per col = 4 slots)
        constexpr int CB = BN * 4;
#pragma unroll
        for (int i = 0; i < CB / 256; ++i) {
            int c = i * 256 + tid;
            int cw = i * 256 + (tid & ~63);
            int col = c >> 2;
            int s = c & 3;
            int g = s ^ (col & 3);
            GLOAD_LDS16(Bb + ((size_t)col * K + k0) * 2 + g * 16,
                        &Bbuf[buf][cw * 16]);
        }
    };

    auto compute = [&](int buf) {
        const char* Ac = Abuf[buf];
        const char* Bc = Bbuf[buf];
        int lr0 = wv * 32 + l15;
        int lr1 = lr0 + 16;
        short8 a0, a1;
        if constexpr (A_BF16) {
            int s0 = q ^ (lr0 & 3);
            int s1 = q ^ (lr1 & 3);
            a0 = *(const short8*)(Ac + lr0 * 64 + s0 * 16);
            a1 = *(const short8*)(Ac + lr1 * 64 + s1 * 16);
        } else {
            int r7a = lr0 & 7, r7b = lr1 & 7;
            float4 f0 = *(const float4*)(Ac + lr0 * 128 + ((2 * q) ^ r7a) * 16);
            float4 f1 = *(const float4*)(Ac + lr0 * 128 + ((2 * q + 1) ^ r7a) * 16);
            float4 f2 = *(const float4*)(Ac + lr1 * 128 + ((2 * q) ^ r7b) * 16);
            float4 f3 = *(const float4*)(Ac + lr1 * 128 + ((2 * q + 1) ^ r7b) * 16);
            a0 = cvt8(f0, f1);
            a1 = cvt8(f2, f3);
        }
#pragma unroll
        for (int ct = 0; ct < NCT; ++ct) {
            int col = ct * 16 + l15;
            int sb = q ^ (col & 3);
            short8 b = *(const short8*)(Bc + col * 64 + sb * 16);
            acc[0][ct] = __builtin_amdgcn_mfma_f32_16x16x32_bf16(a0, b, acc[0][ct], 0, 0, 0);
            acc[1][ct] = __builtin_amdgcn_mfma_f32_16x16x32_bf16(a1, b, acc[1][ct], 0, 0, 0);
        }
    };

    // prologue: 2 tiles in flight (2*SL loads outstanding)
    stage(0, 0);
    stage(1, 32);
#pragma unroll 1
    for (int t = 0; t < NT - 2; ++t) {
        waitvm<SL>();                 // stage(t) landed; stage(t+1) stays in flight
        BAR();
        SCHED0();
        compute(t & 1);
        LGKM0();                      // all ds_reads of buf t&1 executed
        BAR();
        SCHED0();
        stage(t & 1, (t + 2) * 32);   // overwrite consumed buffer with tile t+2
    }
    // tile NT-2 (stage NT-1 still in flight)
    waitvm<SL>();
    BAR();
    SCHED0();
    compute((NT - 2) & 1);
    // tile NT-1 (final drain)
    waitvm<0>();
    BAR();
    SCHED0();
    compute((NT - 1) & 1);

    // epilogue: dinv scale + bf16 store
#pragma unroll
    for (int rt = 0; rt < 2; ++rt) {
#pragma unroll
        for (int reg = 0; reg < 4; ++reg) {
            int row = row0 + wv * 32 + rt * 16 + q * 4 + reg;
            if (row < N) {
                float sc = dinv[row];
#pragma unroll
                for (int ct = 0; ct < NCT; ++ct) {
                    out[(size_t)row * BN + ct * 16 + l15] = f2bf(acc[rt][ct][reg] * sc);
                }
            }
        }
    }
}

// ---------------- aggregation v2: 2 nodes/warp, 8-deep gather pipeline ----------------

__global__ __launch_bounds__(256) void agg1_kernel(
    const uint2* __restrict__ g1v, const int* __restrict__ row_ptr,
    const int* __restrict__ csr_src, const float* __restrict__ dinv,
    const float4* __restrict__ b1v, uint2* __restrict__ h1v) {
    int tid = threadIdx.x;
    int wv = tid >> 6;
    int lane = tid & 63;
    int half = lane >> 5;
    int hl = lane & 31;
    int node = blockIdx.x * 8 + wv * 2 + half;
    uint2 u = g1v[(size_t)node * 32 + hl];
    float a0 = lo_bf(u.x), a1 = hi_bf(u.x), a2 = lo_bf(u.y), a3 = hi_bf(u.y);
    int e = row_ptr[node], end = row_ptr[node + 1];
    for (; e + 8 <= end; e += 8) {
        int j0 = csr_src[e + 0], j1 = csr_src[e + 1], j2 = csr_src[e + 2], j3 = csr_src[e + 3];
        int j4 = csr_src[e + 4], j5 = csr_src[e + 5], j6 = csr_src[e + 6], j7 = csr_src[e + 7];
        uint2 v0 = g1v[(size_t)j0 * 32 + hl];
        uint2 v1 = g1v[(size_t)j1 * 32 + hl];
        uint2 v2 = g1v[(size_t)j2 * 32 + hl];
        uint2 v3 = g1v[(size_t)j3 * 32 + hl];
        uint2 v4 = g1v[(size_t)j4 * 32 + hl];
        uint2 v5 = g1v[(size_t)j5 * 32 + hl];
        uint2 v6 = g1v[(size_t)j6 * 32 + hl];
        uint2 v7 = g1v[(size_t)j7 * 32 + hl];
        a0 += ((lo_bf(v0.x) + lo_bf(v1.x)) + (lo_bf(v2.x) + lo_bf(v3.x))) +
              ((lo_bf(v4.x) + lo_bf(v5.x)) + (lo_bf(v6.x) + lo_bf(v7.x)));
        a1 += ((hi_bf(v0.x) + hi_bf(v1.x)) + (hi_bf(v2.x) + hi_bf(v3.x))) +
              ((hi_bf(v4.x) + hi_bf(v5.x)) + (hi_bf(v6.x) + hi_bf(v7.x)));
        a2 += ((lo_bf(v0.y) + lo_bf(v1.y)) + (lo_bf(v2.y) + lo_bf(v3.y))) +
              ((lo_bf(v4.y) + lo_bf(v5.y)) + (lo_bf(v6.y) + lo_bf(v7.y)));
        a3 += ((hi_bf(v0.y) + hi_bf(v1.y)) + (hi_bf(v2.y) + hi_bf(v3.y))) +
              ((hi_bf(v4.y) + hi_bf(v5.y)) + (hi_bf(v6.y) + hi_bf(v7.y)));
    }
    for (; e + 2 <= end; e += 2) {
        int j0 = csr_src[e + 0], j1 = csr_src[e + 1];
        uint2 v0 = g1v[(size_t)j0 * 32 + hl];
        uint2 v1 = g1v[(size_t)j1 * 32 + hl];
        a0 += lo_bf(v0.x) + lo_bf(v1.x);
        a1 += hi_bf(v0.x) + hi_bf(v1.x);
        a2 += lo_bf(v0.y) + lo_bf(v1.y);
        a3 += hi_bf(v0.y) + hi_bf(v1.y);
    }
    for (; e < end; ++e) {
        uint2 v0 = g1v[(size_t)csr_src[e] * 32 + hl];
        a0 += lo_bf(v0.x);
        a1 += hi_bf(v0.x);
        a2 += lo_bf(v0.y);
        a3 += hi_bf(v0.y);
    }
    float d = dinv[node];
    float4 b = b1v[hl];
    float r0 = fmaxf(d * a0 + b.x, 0.0f);
    float r1 = fmaxf(d * a1 + b.y, 0.0f);
    float r2 = fmaxf(d * a2 + b.z, 0.0f);
    float r3 = fmaxf(d * a3 + b.w, 0.0f);
    h1v[(size_t)node * 32 + hl] = uint2{pack_bf2(r0, r1), pack_bf2(r2, r3)};
}

__global__ __launch_bounds__(256) void agg2_lsm_kernel(
    const unsigned* __restrict__ g2v, const int* __restrict__ row_ptr,
    const int* __restrict__ csr_src, const float* __restrict__ dinv,
    const float2* __restrict__ b2v, float2* __restrict__ outv) {
    int tid = threadIdx.x;
    int wv = tid >> 6;
    int lane = tid & 63;
    int half = lane >> 5;
    int hl = lane & 31;
    int node = blockIdx.x * 8 + wv * 2 + half;
    unsigned u = g2v[(size_t)node * 32 + hl];
    float a0 = lo_bf(u), a1 = hi_bf(u);
    int e = row_ptr[node], end = row_ptr[node + 1];
    for (; e + 8 <= end; e += 8) {
        int j0 = csr_src[e + 0], j1 = csr_src[e + 1], j2 = csr_src[e + 2], j3 = csr_src[e + 3];
        int j4 = csr_src[e + 4], j5 = csr_src[e + 5], j6 = csr_src[e + 6], j7 = csr_src[e + 7];
        unsigned v0 = g2v[(size_t)j0 * 32 + hl];
        unsigned v1 = g2v[(size_t)j1 * 32 + hl];
        unsigned v2 = g2v[(size_t)j2 * 32 + hl];
        unsigned v3 = g2v[(size_t)j3 * 32 + hl];
        unsigned v4 = g2v[(size_t)j4 * 32 + hl];
        unsigned v5 = g2v[(size_t)j5 * 32 + hl];
        unsigned v6 = g2v[(size_t)j6 * 32 + hl];
        unsigned v7 = g2v[(size_t)j7 * 32 + hl];
        a0 += ((lo_bf(v0) + lo_bf(v1)) + (lo_bf(v2) + lo_bf(v3))) +
              ((lo_bf(v4) + lo_bf(v5)) + (lo_bf(v6) + lo_bf(v7)));
        a1 += ((hi_bf(v0) + hi_bf(v1)) + (hi_bf(v2) + hi_bf(v3))) +
              ((hi_bf(v4) + hi_bf(v5)) + (hi_bf(v6) + hi_bf(v7)));
    }
    for (; e + 2 <= end; e += 2) {
        unsigned v0 = g2v[(size_t)csr_src[e + 0] * 32 + hl];
        unsigned v1 = g2v[(size_t)csr_src[e + 1] * 32 + hl];
        a0 += lo_bf(v0) + lo_bf(v1);
        a1 += hi_bf(v0) + hi_bf(v1);
    }
    for (; e < end; ++e) {
        unsigned v0 = g2v[(size_t)csr_src[e] * 32 + hl];
        a0 += lo_bf(v0);
        a1 += hi_bf(v0);
    }
    float d = dinv[node];
    float2 b = b2v[hl];
    float v0 = d * a0 + b.x;
    float v1 = d * a1 + b.y;
    // log-softmax over 64 classes: per-lane pair + 32-lane half reduction
    // (xor offsets <=16 stay within the 32-lane half)
    float m = fmaxf(v0, v1);
#pragma unroll
    for (int o = 16; o > 0; o >>= 1) m = fmaxf(m, __shfl_xor(m, o, 64));
    float s = __expf(v0 - m) + __expf(v1 - m);
#pragma unroll
    for (int o = 16; o > 0; o >>= 1) s += __shfl_xor(s, o, 64);
    float ls = __logf(s);
    outv[(size_t)node * 32 + hl] = float2{v0 - m - ls, v1 - m - ls};
}

// ---------------- launch ----------------

extern "C" void kernel_launch(void* const* d_in, const int* in_sizes, int n_in,
                              void* d_out, int out_size, void* d_ws, size_t ws_size,
                              hipStream_t stream) {
    const float* x  = (const float*)d_in[0];
    const int* eidx = (const int*)d_in[1];
    const float* W1 = (const float*)d_in[2];
    const float* b1 = (const float*)d_in[3];
    const float* W2 = (const float*)d_in[4];
    const float* b2 = (const float*)d_in[5];
    float* out = (float*)d_out;
    const int* src = eidx;
    const int* dst = eidx + N_EDGES;

    char* base = (char*)d_ws;
    size_t off = 0;
    auto alloc = [&](size_t bytes) -> void* {
        void* p = base + off;
        off += (bytes + 255) & ~(size_t)255;
        return p;
    };
    // zero-init region: [deg | gcur | ovcnt] — one memset
    int* zbase    = (int*)alloc((size_t)(N_NODES + NBUK + 64) * 4);
    int* deg      = zbase;
    int* gcur     = zbase + N_NODES;
    int* ovcnt    = zbase + N_NODES + NBUK;
    int* row_ptr  = (int*)alloc((size_t)(N_NODES + 1) * 4);
    float* dinv   = (float*)alloc((size_t)N_NODES * 4);
    int* bsum     = (int*)alloc((size_t)SCAN_NB * 4);
    unsigned* staging = (unsigned*)alloc((size_t)NBUK * SCAP * 4);   // 9.6 MB
    unsigned long long* ovbuf = (unsigned long long*)alloc((size_t)OV_CAP * 8);
    int* csr_src  = (int*)alloc((size_t)N_EDGES * 4);
    unsigned short* Wt1 = (unsigned short*)alloc((size_t)F_HID * F_IN * 2);
    unsigned short* Wt2 = (unsigned short*)alloc((size_t)F_OUT * F_HID * 2);
    unsigned short* g1  = (unsigned short*)alloc((size_t)N_NODES * F_HID * 2);
    unsigned short* h1  = (unsigned short*)alloc((size_t)N_NODES * F_HID * 2);
    unsigned short* g2  = g1;  // g1 dead after agg1

    hipMemsetAsync(zbase, 0, (size_t)(N_NODES + NBUK + 64) * 4, stream);
    partition_kernel<<<NBLK_A, 256, 0, stream>>>(src, dst, deg, staging, gcur, ovbuf, ovcnt);
    block_sum_kernel<<<SCAN_NB, 256, 0, stream>>>(deg, bsum, N_NODES);
    scan_partials_kernel<<<1, 512, 0, stream>>>(bsum, SCAN_NB);
    scan_final_kernel<<<SCAN_NB, 256, 0, stream>>>(deg, bsum, row_ptr, dinv, N_NODES);
    fill_kernel<<<NBUK * FILL_SPLIT, 256, 0, stream>>>(staging, gcur, row_ptr, csr_src, ovbuf, ovcnt);
    transpose_w_kernel<<<(F_HID * F_IN + F_OUT * F_HID + 255) / 256, 256, 0, stream>>>(
        W1, W2, Wt1, Wt2);

    int gblocks = (N_NODES + 127) / 128;  // 782
    gemm_lds_kernel<F_HID, F_IN, false><<<gblocks, 256, 0, stream>>>(
        (const void*)x, Wt1, dinv, g1, N_NODES);
    agg1_kernel<<<N_NODES / 8, 256, 0, stream>>>(
        (const uint2*)g1, row_ptr, csr_src, dinv, (const float4*)b1, (uint2*)h1);

    gemm_lds_kernel<F_OUT, F_HID, true><<<gblocks, 256, 0, stream>>>(
        (const void*)h1, Wt2, dinv, g2, N_NODES);
    agg2_lsm_kernel<<<N_NODES / 8, 256, 0, stream>>>(
        (const unsigned*)g2, row_ptr, csr_src, dinv, (const float2*)b2, (float2*)out);
}

// Round 8
// 500.883 us; speedup vs baseline: 1.2152x; 1.1130x over previous
//
#include <hip/hip_runtime.h>
#include <cmath>

#define N_NODES 100000
#define N_EDGES 1600000
#define F_IN 512
#define F_HID 128
#define F_OUT 64

#define SCAN_NB ((N_NODES + 255) / 256)   // 391 blocks

// ---- bucketed CSR-build params ----
#define BK_SHIFT 10                        // 1024 nodes per bucket
#define NBUK ((N_NODES + 1023) >> 10)      // 98 buckets
#define SCAP 24576                         // staging capacity/bucket (mean 16327, +65 sigma)
#define LSLOT 64                           // LDS slots per bucket
#define NBLK_A 512                         // partition blocks (2/CU)
#define FILL_SPLIT 8                       // slice-blocks per bucket, disjoint node ranges
#define NPS (1024 / FILL_SPLIT)            // 128 nodes per slice
#define OV_CAP 4096                        // global overflow records

typedef __attribute__((ext_vector_type(8))) short short8;
typedef __attribute__((ext_vector_type(4))) float float4v;

// async global->LDS, 16B per lane; LDS dest is wave-uniform base + lane*16
#define GLOAD_LDS16(g, l)                                                      \
    __builtin_amdgcn_global_load_lds(                                          \
        (const __attribute__((address_space(1))) void*)(g),                    \
        (__attribute__((address_space(3))) void*)(l), 16, 0, 0)

__device__ __forceinline__ unsigned short f2bf(float f) {
    unsigned u = __builtin_bit_cast(unsigned, f);
    u += 0x7FFFu + ((u >> 16) & 1u);   // RNE
    return (unsigned short)(u >> 16);
}
__device__ __forceinline__ float bf2f(unsigned short s) {
    unsigned u = ((unsigned)s) << 16;
    return __builtin_bit_cast(float, u);
}
__device__ __forceinline__ float lo_bf(unsigned u) {
    return __builtin_bit_cast(float, u << 16);
}
__device__ __forceinline__ float hi_bf(unsigned u) {
    return __builtin_bit_cast(float, u & 0xFFFF0000u);
}
__device__ __forceinline__ short8 cvt8(float4 lo, float4 hi) {
    return short8{(short)f2bf(lo.x), (short)f2bf(lo.y), (short)f2bf(lo.z), (short)f2bf(lo.w),
                  (short)f2bf(hi.x), (short)f2bf(hi.y), (short)f2bf(hi.z), (short)f2bf(hi.w)};
}
__device__ __forceinline__ unsigned pack_bf2(float a, float b) {
    return (unsigned)f2bf(a) | ((unsigned)f2bf(b) << 16);
}

// counted vmcnt wait (template-dispatched literal; asm needs an immediate)
template <int N>
__device__ __forceinline__ void waitvm() {
    if constexpr (N == 0) asm volatile("s_waitcnt vmcnt(0)" ::: "memory");
    else if constexpr (N == 3) asm volatile("s_waitcnt vmcnt(3)" ::: "memory");
    else if constexpr (N == 6) asm volatile("s_waitcnt vmcnt(6)" ::: "memory");
    else static_assert(N == 0 || N == 3 || N == 6, "add literal");
}
#define LGKM0() asm volatile("s_waitcnt lgkmcnt(0)" ::: "memory")
#define BAR() __builtin_amdgcn_s_barrier()
#define SCHED0() __builtin_amdgcn_sched_barrier(0)

// ---------------- partition: edges -> per-bucket staging (NO global deg atomics) ----------------
// R11: deg is now derived from staging by deg_hist_kernel -> the 1.6M scattered
// global atomicAdd(&deg[d]) are gone from the hot loop. Per edge: LDS atomic +
// LDS store only; staging writes remain dense append via gcur.
__global__ __launch_bounds__(256) void partition_kernel(
    const int* __restrict__ src, const int* __restrict__ dst,
    unsigned* __restrict__ staging, int* __restrict__ gcur,
    unsigned long long* __restrict__ ovbuf, int* __restrict__ ovcnt) {
    __shared__ unsigned buf[NBUK][LSLOT];
    __shared__ int cnt[NBUK];
    int tid = threadIdx.x;
    for (int b = tid; b < NBUK; b += 256) cnt[b] = 0;
    __syncthreads();
    constexpr int PER = (((N_EDGES + NBLK_A - 1) / NBLK_A) + 3) & ~3;   // 3128
    int e0 = blockIdx.x * PER;
    int e1 = min(e0 + PER, N_EDGES);

    auto body = [&](int d, int s) {
        int b = d >> BK_SHIFT;
        unsigned rec = (unsigned)s | ((unsigned)(d & 1023) << 17);
        int slot = atomicAdd(&cnt[b], 1);
        if (slot < LSLOT) {
            buf[b][slot] = rec;
        } else {  // rare LDS overflow: spill (src,dst) to global list
            int op = atomicAdd(ovcnt, 1);
            if (op < OV_CAP)
                ovbuf[op] = ((unsigned long long)(unsigned)d << 32) | (unsigned)s;
        }
    };
    auto drain = [&](void) {
        for (int b = tid; b < NBUK; b += 256) {
            int c = min(cnt[b], LSLOT);
            int full = c & ~15;
            if (full > 0) {
                int pos = atomicAdd(&gcur[b], full);
                if (pos + full <= SCAP) {
                    unsigned* dp = &staging[(size_t)b * SCAP + pos];
                    for (int i = 0; i < full; ++i) dp[i] = buf[b][i];
                }
                for (int i = 0; i < c - full; ++i) buf[b][i] = buf[b][full + i];
            }
            cnt[b] = c - full;
        }
    };

    int base = e0;
    for (; base + 1024 <= e1; base += 1024) {
        int e = base + tid * 4;
        int4 dv = *(const int4*)(dst + e);   // 16B vectorized edge loads
        int4 sv = *(const int4*)(src + e);
        body(dv.x, sv.x);
        body(dv.y, sv.y);
        body(dv.z, sv.z);
        body(dv.w, sv.w);
        __syncthreads();
        drain();
        __syncthreads();
    }
    // tail (<1024 edges), scalar
    for (int e = base + tid; e < e1; e += 256) body(dst[e], src[e]);
    __syncthreads();
    drain();
    __syncthreads();
    // final flush of remainders
    for (int b = tid; b < NBUK; b += 256) {
        int c = cnt[b];
        if (c > 0) {
            int pos = atomicAdd(&gcur[b], c);
            if (pos + c <= SCAP)
                for (int i = 0; i < c; ++i) staging[(size_t)b * SCAP + pos + i] = buf[b][i];
        }
    }
}

// ---------------- deg_hist: per-bucket LDS histogram -> deg ----------------
// One block per bucket: 1024 LDS counters, vectorized staging scan + overflow
// replay, coalesced deg write. deg is exactly consistent with what fill inserts
// (both derive from staging+ovbuf), even under (never-observed) staging loss.
__global__ __launch_bounds__(256) void deg_hist_kernel(
    const unsigned* __restrict__ staging, const int* __restrict__ gcur,
    const unsigned long long* __restrict__ ovbuf, const int* __restrict__ ovcnt,
    int* __restrict__ deg) {
    int b = blockIdx.x;
    __shared__ int hist[1024];
    int tid = threadIdx.x;
    for (int i = tid; i < 1024; i += 256) hist[i] = 0;
    __syncthreads();
    int n = gcur[b];
    if (n > SCAP) n = SCAP;
    const unsigned* sp = &staging[(size_t)b * SCAP];
    int i = tid * 4;
    for (; i + 4 <= n; i += 1024) {
        uint4 r = *(const uint4*)(sp + i);
        atomicAdd(&hist[r.x >> 17], 1);
        atomicAdd(&hist[r.y >> 17], 1);
        atomicAdd(&hist[r.z >> 17], 1);
        atomicAdd(&hist[r.w >> 17], 1);
    }
    int tail0 = n & ~3;
    if (tid < (n - tail0)) atomicAdd(&hist[sp[tail0 + tid] >> 17], 1);
    int oc = *ovcnt;
    if (oc > OV_CAP) oc = OV_CAP;
    for (int k = tid; k < oc; k += 256) {
        int d = (int)(ovbuf[k] >> 32);
        if ((d >> BK_SHIFT) == b) atomicAdd(&hist[d & 1023], 1);
    }
    __syncthreads();
    int node0 = b << BK_SHIFT;
    for (int j = tid; j < 1024; j += 256) {
        int nd = node0 + j;
        if (nd < N_NODES) deg[nd] = hist[j];
    }
}

// ---------------- fill: slice-owned node ranges + LDS cursors ----------------
__global__ __launch_bounds__(256) void fill_kernel(
    const unsigned* __restrict__ staging, const int* __restrict__ gcur,
    const int* __restrict__ row_ptr, int* __restrict__ csr_src,
    const unsigned long long* __restrict__ ovbuf, const int* __restrict__ ovcnt) {
    int b = blockIdx.x / FILL_SPLIT;
    int slice = blockIdx.x - b * FILL_SPLIT;
    int dl0 = slice * NPS;                  // first local node of this slice
    int node0 = (b << BK_SHIFT) + dl0;
    __shared__ int lcur[NPS];
    int tid = threadIdx.x;
    if (tid < NPS) {
        int nd = node0 + tid;
        lcur[tid] = (nd < N_NODES) ? row_ptr[nd] : 0;
    }
    __syncthreads();

    int n = gcur[b];
    if (n > SCAP) n = SCAP;
    const unsigned* sp = &staging[(size_t)b * SCAP];

    auto process = [&](unsigned rec) {
        int dl = (int)(rec >> 17) - dl0;
        if ((unsigned)dl < (unsigned)NPS) {
            int pos = atomicAdd(&lcur[dl], 1);
            csr_src[pos] = (int)(rec & 0x1FFFFu);
        }
    };

    int i = tid * 4;
    for (; i + 4 <= n; i += 1024) {
        uint4 r = *(const uint4*)(sp + i);
        process(r.x);
        process(r.y);
        process(r.z);
        process(r.w);
    }
    int tail0 = n & ~3;
    if (tid < (n - tail0)) process(sp[tail0 + tid]);

    int oc = *ovcnt;
    if (oc > OV_CAP) oc = OV_CAP;
    for (int k = tid; k < oc; k += 256) {
        unsigned long long r = ovbuf[k];
        int d = (int)(r >> 32);
        int dl = d - node0;
        if ((d >> BK_SHIFT) == b && (unsigned)dl < (unsigned)NPS) {
            int pos = atomicAdd(&lcur[dl], 1);
            csr_src[pos] = (int)(r & 0xffffffffu);
        }
    }
}

// ---------------- scans ----------------

__global__ __launch_bounds__(256) void block_sum_kernel(const int* __restrict__ deg,
                                                        int* __restrict__ bsum, int n) {
    int g = blockIdx.x * 256 + threadIdx.x;
    int v = (g < n) ? deg[g] : 0;
    __shared__ int ws[4];
    int lane = threadIdx.x & 63;
    int w = threadIdx.x >> 6;
#pragma unroll
    for (int o = 32; o > 0; o >>= 1) v += __shfl_down(v, o, 64);
    if (lane == 0) ws[w] = v;
    __syncthreads();
    if (threadIdx.x == 0) bsum[blockIdx.x] = ws[0] + ws[1] + ws[2] + ws[3];
}

__global__ __launch_bounds__(512) void scan_partials_kernel(int* __restrict__ bsum, int nb) {
    __shared__ int t[512];
    int tid = threadIdx.x;
    int v = (tid < nb) ? bsum[tid] : 0;
    t[tid] = v;
    __syncthreads();
    for (int d = 1; d < 512; d <<= 1) {
        int u = (tid >= d) ? t[tid - d] : 0;
        __syncthreads();
        t[tid] += u;
        __syncthreads();
    }
    if (tid < nb) bsum[tid] = t[tid] - v;  // exclusive
}

__global__ __launch_bounds__(256) void scan_final_kernel(const int* __restrict__ deg,
                                                         const int* __restrict__ bsum,
                                                         int* __restrict__ row_ptr,
                                                         float* __restrict__ dinv, int n) {
    __shared__ int t[256];
    int g = blockIdx.x * 256 + threadIdx.x;
    int tid = threadIdx.x;
    int v = (g < n) ? deg[g] : 0;
    t[tid] = v;
    __syncthreads();
    for (int d = 1; d < 256; d <<= 1) {
        int u = (tid >= d) ? t[tid - d] : 0;
        __syncthreads();
        t[tid] += u;
        __syncthreads();
    }
    int off = bsum[blockIdx.x] + t[tid] - v;
    if (g < n) {
        row_ptr[g] = off;
        dinv[g] = rsqrtf((float)(v + 1));
    }
    if (g == n - 1) row_ptr[n] = off + v;
}

// ---------------- W transpose+convert: Wt[n][k] bf16 ----------------

__global__ void transpose_w_kernel(const float* __restrict__ W1, const float* __restrict__ W2,
                                   unsigned short* __restrict__ Wt1,
                                   unsigned short* __restrict__ Wt2) {
    int g = blockIdx.x * 256 + threadIdx.x;
    if (g < F_HID * F_IN) {               // Wt1: [128][512]
        int n = g >> 9, k = g & 511;
        Wt1[g] = f2bf(W1[k * F_HID + n]);
    } else {
        int h = g - F_HID * F_IN;         // Wt2: [64][128]
        if (h < F_OUT * F_HID) {
            int n = h >> 7, k = h & 127;
            Wt2[h] = f2bf(W2[k * F_OUT + n]);
        }
    }
}

// ---------------- LDS-staged MFMA GEMM, counted-vmcnt pipeline (T3+T4) ----------------

template <int BN, int K, bool A_BF16>
__global__ __launch_bounds__(256, 3) void gemm_lds_kernel(
    const void* __restrict__ Araw, const unsigned short* __restrict__ Wt,
    const float* __restrict__ dinv, unsigned short* __restrict__ out, int N) {
    constexpr int NCT = BN / 16;
    constexpr int AE = A_BF16 ? 2 : 4;         // A element bytes
    constexpr int SLOTS_A = (32 * AE) / 16;    // 16B slots per row per 32-k chunk (4 or 8)
    constexpr int MA = SLOTS_A - 1;
    constexpr int ABYTES = 128 * 32 * AE;      // per A buffer (8K or 16K)
    constexpr int BBYTES = BN * 32 * 2;        // per B buffer (4K or 8K)
    constexpr int NT = K / 32;
    constexpr int SL = (128 * SLOTS_A + BN * 4) / 256;  // gload_lds per stage: 6 (gemm1) / 3 (gemm2)

    __shared__ __align__(128) char Abuf[2][ABYTES];
    __shared__ __align__(128) char Bbuf[2][BBYTES];

    const char* Ab = (const char*)Araw;
    const char* Bb = (const char*)Wt;
    int tid = threadIdx.x;
    int lane = tid & 63;
    int wv = tid >> 6;
    int row0 = blockIdx.x * 128;
    int l15 = lane & 15;
    int q = lane >> 4;

    float4v acc[2][NCT] = {};

    auto stage = [&](int buf, int k0) {
        // A: 128 rows x 32 elems, 16B chunks; chunk c -> row c/SLOTS_A, slot c%SLOTS_A
        constexpr int CA = 128 * SLOTS_A;
#pragma unroll
        for (int i = 0; i < CA / 256; ++i) {
            int c = i * 256 + tid;
            int cw = i * 256 + (tid & ~63);      // wave-uniform chunk base
            int row = c / SLOTS_A;
            int s = c & MA;
            int g = s ^ (row & MA);              // inverse swizzle on SOURCE
            int rg = row0 + row;
            if (rg >= N) rg = N - 1;             // clamp (last block tail)
            GLOAD_LDS16(Ab + ((size_t)rg * K + k0) * AE + g * 16,
                        &Abuf[buf][cw * 16]);
        }
        // B: BN cols x 32 k bf16 (64B per col = 4 slots)
        constexpr int CB = BN * 4;
#pragma unroll
        for (int i = 0; i < CB / 256; ++i) {
            int c = i * 256 + tid;
            int cw = i * 256 + (tid & ~63);
            int col = c >> 2;
            int s = c & 3;
            int g = s ^ (col & 3);
            GLOAD_LDS16(Bb + ((size_t)col * K + k0) * 2 + g * 16,
                        &Bbuf[buf][cw * 16]);
        }
    };

    auto compute = [&](int buf) {
        const char* Ac = Abuf[buf];
        const char* Bc = Bbuf[buf];
        int lr0 = wv * 32 + l15;
        int lr1 = lr0 + 16;
        short8 a0, a1;
        if constexpr (A_BF16) {
            int s0 = q ^ (lr0 & 3);
            int s1 = q ^ (lr1 & 3);
            a0 = *(const short8*)(Ac + lr0 * 64 + s0 * 16);
            a1 = *(const short8*)(Ac + lr1 * 64 + s1 * 16);
        } else {
            int r7a = lr0 & 7, r7b = lr1 & 7;
            float4 f0 = *(const float4*)(Ac + lr0 * 128 + ((2 * q) ^ r7a) * 16);
            float4 f1 = *(const float4*)(Ac + lr0 * 128 + ((2 * q + 1) ^ r7a) * 16);
            float4 f2 = *(const float4*)(Ac + lr1 * 128 + ((2 * q) ^ r7b) * 16);
            float4 f3 = *(const float4*)(Ac + lr1 * 128 + ((2 * q + 1) ^ r7b) * 16);
            a0 = cvt8(f0, f1);
            a1 = cvt8(f2, f3);
        }
#pragma unroll
        for (int ct = 0; ct < NCT; ++ct) {
            int col = ct * 16 + l15;
            int sb = q ^ (col & 3);
            short8 b = *(const short8*)(Bc + col * 64 + sb * 16);
            acc[0][ct] = __builtin_amdgcn_mfma_f32_16x16x32_bf16(a0, b, acc[0][ct], 0, 0, 0);
            acc[1][ct] = __builtin_amdgcn_mfma_f32_16x16x32_bf16(a1, b, acc[1][ct], 0, 0, 0);
        }
    };

    // prologue: 2 tiles in flight (2*SL loads outstanding)
    stage(0, 0);
    stage(1, 32);
#pragma unroll 1
    for (int t = 0; t < NT - 2; ++t) {
        waitvm<SL>();                 // stage(t) landed; stage(t+1) stays in flight
        BAR();
        SCHED0();
        compute(t & 1);
        LGKM0();                      // all ds_reads of buf t&1 executed
        BAR();
        SCHED0();
        stage(t & 1, (t + 2) * 32);   // overwrite consumed buffer with tile t+2
    }
    // tile NT-2 (stage NT-1 still in flight)
    waitvm<SL>();
    BAR();
    SCHED0();
    compute((NT - 2) & 1);
    // tile NT-1 (final drain)
    waitvm<0>();
    BAR();
    SCHED0();
    compute((NT - 1) & 1);

    // epilogue: dinv scale + bf16 store
#pragma unroll
    for (int rt = 0; rt < 2; ++rt) {
#pragma unroll
        for (int reg = 0; reg < 4; ++reg) {
            int row = row0 + wv * 32 + rt * 16 + q * 4 + reg;
            if (row < N) {
                float sc = dinv[row];
#pragma unroll
                for (int ct = 0; ct < NCT; ++ct) {
                    out[(size_t)row * BN + ct * 16 + l15] = f2bf(acc[rt][ct][reg] * sc);
                }
            }
        }
    }
}

// ---------------- aggregation v3: 4 nodes/wave (16-lane quarters), wider gathers ----------------
// R11: agg1 rows gathered as uint4 (16B/lane x 16 lanes = 256B row in ONE inst),
// agg2 as uint2. 4 nodes/wave x 8-deep = 32 gathers in flight per wave (2x R8).
// 100000 = 6250 blocks * 16 nodes exactly.

__global__ __launch_bounds__(256) void agg1_kernel(
    const uint4* __restrict__ g1v, const int* __restrict__ row_ptr,
    const int* __restrict__ csr_src, const float* __restrict__ dinv,
    const float4* __restrict__ b1v, uint4* __restrict__ h1v) {
    int tid = threadIdx.x;
    int wv = tid >> 6;
    int lane = tid & 63;
    int qt = lane >> 4;
    int ql = lane & 15;
    int node = blockIdx.x * 16 + wv * 4 + qt;
    uint4 u = g1v[(size_t)node * 16 + ql];
    float a0 = lo_bf(u.x), a1 = hi_bf(u.x), a2 = lo_bf(u.y), a3 = hi_bf(u.y);
    float a4 = lo_bf(u.z), a5 = hi_bf(u.z), a6 = lo_bf(u.w), a7 = hi_bf(u.w);
    int e = row_ptr[node], end = row_ptr[node + 1];
#define ACC8(v)                                                                \
    a0 += lo_bf(v.x); a1 += hi_bf(v.x); a2 += lo_bf(v.y); a3 += hi_bf(v.y);    \
    a4 += lo_bf(v.z); a5 += hi_bf(v.z); a6 += lo_bf(v.w); a7 += hi_bf(v.w)
    for (; e + 8 <= end; e += 8) {
        int j0 = csr_src[e + 0], j1 = csr_src[e + 1], j2 = csr_src[e + 2], j3 = csr_src[e + 3];
        int j4 = csr_src[e + 4], j5 = csr_src[e + 5], j6 = csr_src[e + 6], j7 = csr_src[e + 7];
        uint4 v0 = g1v[(size_t)j0 * 16 + ql];
        uint4 v1 = g1v[(size_t)j1 * 16 + ql];
        uint4 v2 = g1v[(size_t)j2 * 16 + ql];
        uint4 v3 = g1v[(size_t)j3 * 16 + ql];
        uint4 v4 = g1v[(size_t)j4 * 16 + ql];
        uint4 v5 = g1v[(size_t)j5 * 16 + ql];
        uint4 v6 = g1v[(size_t)j6 * 16 + ql];
        uint4 v7 = g1v[(size_t)j7 * 16 + ql];
        ACC8(v0); ACC8(v1); ACC8(v2); ACC8(v3);
        ACC8(v4); ACC8(v5); ACC8(v6); ACC8(v7);
    }
    for (; e + 2 <= end; e += 2) {
        uint4 v0 = g1v[(size_t)csr_src[e + 0] * 16 + ql];
        uint4 v1 = g1v[(size_t)csr_src[e + 1] * 16 + ql];
        ACC8(v0); ACC8(v1);
    }
    for (; e < end; ++e) {
        uint4 v0 = g1v[(size_t)csr_src[e] * 16 + ql];
        ACC8(v0);
    }
#undef ACC8
    float d = dinv[node];
    float4 ba = b1v[2 * ql], bb = b1v[2 * ql + 1];
    float r0 = fmaxf(d * a0 + ba.x, 0.0f), r1 = fmaxf(d * a1 + ba.y, 0.0f);
    float r2 = fmaxf(d * a2 + ba.z, 0.0f), r3 = fmaxf(d * a3 + ba.w, 0.0f);
    float r4 = fmaxf(d * a4 + bb.x, 0.0f), r5 = fmaxf(d * a5 + bb.y, 0.0f);
    float r6 = fmaxf(d * a6 + bb.z, 0.0f), r7 = fmaxf(d * a7 + bb.w, 0.0f);
    h1v[(size_t)node * 16 + ql] =
        uint4{pack_bf2(r0, r1), pack_bf2(r2, r3), pack_bf2(r4, r5), pack_bf2(r6, r7)};
}

__global__ __launch_bounds__(256) void agg2_lsm_kernel(
    const uint2* __restrict__ g2v, const int* __restrict__ row_ptr,
    const int* __restrict__ csr_src, const float* __restrict__ dinv,
    const float4* __restrict__ b2v, float4* __restrict__ outv) {
    int tid = threadIdx.x;
    int wv = tid >> 6;
    int lane = tid & 63;
    int qt = lane >> 4;
    int ql = lane & 15;
    int node = blockIdx.x * 16 + wv * 4 + qt;
    uint2 u = g2v[(size_t)node * 16 + ql];
    float a0 = lo_bf(u.x), a1 = hi_bf(u.x), a2 = lo_bf(u.y), a3 = hi_bf(u.y);
    int e = row_ptr[node], end = row_ptr[node + 1];
#define ACC4(v)                                                                \
    a0 += lo_bf(v.x); a1 += hi_bf(v.x); a2 += lo_bf(v.y); a3 += hi_bf(v.y)
    for (; e + 8 <= end; e += 8) {
        int j0 = csr_src[e + 0], j1 = csr_src[e + 1], j2 = csr_src[e + 2], j3 = csr_src[e + 3];
        int j4 = csr_src[e + 4], j5 = csr_src[e + 5], j6 = csr_src[e + 6], j7 = csr_src[e + 7];
        uint2 v0 = g2v[(size_t)j0 * 16 + ql];
        uint2 v1 = g2v[(size_t)j1 * 16 + ql];
        uint2 v2 = g2v[(size_t)j2 * 16 + ql];
        uint2 v3 = g2v[(size_t)j3 * 16 + ql];
        uint2 v4 = g2v[(size_t)j4 * 16 + ql];
        uint2 v5 = g2v[(size_t)j5 * 16 + ql];
        uint2 v6 = g2v[(size_t)j6 * 16 + ql];
        uint2 v7 = g2v[(size_t)j7 * 16 + ql];
        ACC4(v0); ACC4(v1); ACC4(v2); ACC4(v3);
        ACC4(v4); ACC4(v5); ACC4(v6); ACC4(v7);
    }
    for (; e + 2 <= end; e += 2) {
        uint2 v0 = g2v[(size_t)csr_src[e + 0] * 16 + ql];
        uint2 v1 = g2v[(size_t)csr_src[e + 1] * 16 + ql];
        ACC4(v0); ACC4(v1);
    }
    for (; e < end; ++e) {
        uint2 v0 = g2v[(size_t)csr_src[e] * 16 + ql];
        ACC4(v0);
    }
#undef ACC4
    float d = dinv[node];
    float4 b = b2v[ql];
    float v0 = d * a0 + b.x;
    float v1 = d * a1 + b.y;
    float v2 = d * a2 + b.z;
    float v3 = d * a3 + b.w;
    // log-softmax over 64 classes: 4 values/lane + 16-lane quarter reduction
    // (xor offsets <=8 stay within the 16-lane quarter)
    float m = fmaxf(fmaxf(v0, v1), fmaxf(v2, v3));
#pragma unroll
    for (int o = 8; o > 0; o >>= 1) m = fmaxf(m, __shfl_xor(m, o, 64));
    float s = __expf(v0 - m) + __expf(v1 - m) + __expf(v2 - m) + __expf(v3 - m);
#pragma unroll
    for (int o = 8; o > 0; o >>= 1) s += __shfl_xor(s, o, 64);
    float ls = m + __logf(s);
    outv[(size_t)node * 16 + ql] = float4{v0 - ls, v1 - ls, v2 - ls, v3 - ls};
}

// ---------------- launch ----------------

extern "C" void kernel_launch(void* const* d_in, const int* in_sizes, int n_in,
                              void* d_out, int out_size, void* d_ws, size_t ws_size,
                              hipStream_t stream) {
    const float* x  = (const float*)d_in[0];
    const int* eidx = (const int*)d_in[1];
    const float* W1 = (const float*)d_in[2];
    const float* b1 = (const float*)d_in[3];
    const float* W2 = (const float*)d_in[4];
    const float* b2 = (const float*)d_in[5];
    float* out = (float*)d_out;
    const int* src = eidx;
    const int* dst = eidx + N_EDGES;

    char* base = (char*)d_ws;
    size_t off = 0;
    auto alloc = [&](size_t bytes) -> void* {
        void* p = base + off;
        off += (bytes + 255) & ~(size_t)255;
        return p;
    };
    // zero-init region: [gcur | ovcnt] — one small memset (deg fully written by deg_hist)
    int* zbase    = (int*)alloc((size_t)(NBUK + 64) * 4);
    int* gcur     = zbase;
    int* ovcnt    = zbase + NBUK;
    int* deg      = (int*)alloc((size_t)N_NODES * 4);
    int* row_ptr  = (int*)alloc((size_t)(N_NODES + 1) * 4);
    float* dinv   = (float*)alloc((size_t)N_NODES * 4);
    int* bsum     = (int*)alloc((size_t)SCAN_NB * 4);
    unsigned* staging = (unsigned*)alloc((size_t)NBUK * SCAP * 4);   // 9.6 MB
    unsigned long long* ovbuf = (unsigned long long*)alloc((size_t)OV_CAP * 8);
    int* csr_src  = (int*)alloc((size_t)N_EDGES * 4);
    unsigned short* Wt1 = (unsigned short*)alloc((size_t)F_HID * F_IN * 2);
    unsigned short* Wt2 = (unsigned short*)alloc((size_t)F_OUT * F_HID * 2);
    unsigned short* g1  = (unsigned short*)alloc((size_t)N_NODES * F_HID * 2);
    unsigned short* h1  = (unsigned short*)alloc((size_t)N_NODES * F_HID * 2);
    unsigned short* g2  = g1;  // g1 dead after agg1

    hipMemsetAsync(zbase, 0, (size_t)(NBUK + 64) * 4, stream);
    partition_kernel<<<NBLK_A, 256, 0, stream>>>(src, dst, staging, gcur, ovbuf, ovcnt);
    deg_hist_kernel<<<NBUK, 256, 0, stream>>>(staging, gcur, ovbuf, ovcnt, deg);
    block_sum_kernel<<<SCAN_NB, 256, 0, stream>>>(deg, bsum, N_NODES);
    scan_partials_kernel<<<1, 512, 0, stream>>>(bsum, SCAN_NB);
    scan_final_kernel<<<SCAN_NB, 256, 0, stream>>>(deg, bsum, row_ptr, dinv, N_NODES);
    fill_kernel<<<NBUK * FILL_SPLIT, 256, 0, stream>>>(staging, gcur, row_ptr, csr_src, ovbuf, ovcnt);
    transpose_w_kernel<<<(F_HID * F_IN + F_OUT * F_HID + 255) / 256, 256, 0, stream>>>(
        W1, W2, Wt1, Wt2);

    int gblocks = (N_NODES + 127) / 128;  // 782
    gemm_lds_kernel<F_HID, F_IN, false><<<gblocks, 256, 0, stream>>>(
        (const void*)x, Wt1, dinv, g1, N_NODES);
    agg1_kernel<<<N_NODES / 16, 256, 0, stream>>>(
        (const uint4*)g1, row_ptr, csr_src, dinv, (const float4*)b1, (uint4*)h1);

    gemm_lds_kernel<F_OUT, F_HID, true><<<gblocks, 256, 0, stream>>>(
        (const void*)h1, Wt2, dinv, g2, N_NODES);
    agg2_lsm_kernel<<<N_NODES / 16, 256, 0, stream>>>(
        (const uint2*)g2, row_ptr, csr_src, dinv, (const float4*)b2, (float4*)out);
}